// Round 6
// baseline (1535.162 us; speedup 1.0000x reference)
//
#include <hip/hip_runtime.h>
#include <stdint.h>

#define B_ 512
#define L_ 48
#define D_ 256

typedef __attribute__((ext_vector_type(8))) short bf16x8;
typedef __attribute__((ext_vector_type(4))) short bf16x4;
typedef __attribute__((ext_vector_type(4))) float f32x4;

__device__ __forceinline__ short f2bf(float f) {
    union { float f; unsigned u; } v; v.f = f;
    unsigned u = v.u;
    unsigned r = (u + 0x7FFFu + ((u >> 16) & 1u)) >> 16;
    return (short)r;
}
__device__ __forceinline__ float bf2f(short s) {
    union { unsigned u; float f; } v; v.u = ((unsigned)(unsigned short)s) << 16;
    return v.f;
}

// ---------------- weight prep: fp32 -> bf16, concat [w_hh;w_h] ----------------
__global__ __launch_bounds__(256) void k_prep(const float* __restrict__ w_hh,
                                              const float* __restrict__ w_h,
                                              const float* __restrict__ w_ih,
                                              short* __restrict__ W1,
                                              short* __restrict__ W2) {
    int t = blockIdx.x * 256 + threadIdx.x;
    const int N1 = 768 * 256;
    const int N1b = 816 * 256;
    if (t < N1) {
        W1[t] = f2bf(w_hh[t]);
    } else if (t < N1b) {
        W1[t] = f2bf(w_h[t - N1]);
    } else {
        int u = t - N1b;
        if (u < 768 * 256) W2[u] = f2bf(w_ih[u]);
    }
}

// ---------------- embedding GEMM: x = relu(x1@we1^T+b1) + relu(x2@we2^T+b2) ----
__device__ __forceinline__ void gemm_pass(const float* __restrict__ X,
                                          const float* __restrict__ W,
                                          short (*sA)[40], short (*sB)[40],
                                          int m0, int n0, int srow, int sseg,
                                          int mf, int nf, int row16, int kg,
                                          f32x4 (&acc)[2][4]) {
    for (int k0 = 0; k0 < 512; k0 += 32) {
        __syncthreads();
        {
            const float* src = X + (size_t)(m0 + srow) * 512 + k0 + sseg * 8;
            float4 p0 = *(const float4*)(src);
            float4 p1 = *(const float4*)(src + 4);
            bf16x8 v;
            v[0] = f2bf(p0.x); v[1] = f2bf(p0.y); v[2] = f2bf(p0.z); v[3] = f2bf(p0.w);
            v[4] = f2bf(p1.x); v[5] = f2bf(p1.y); v[6] = f2bf(p1.z); v[7] = f2bf(p1.w);
            *(bf16x8*)&sA[srow][sseg * 8] = v;
        }
        {
            const float* src = W + (size_t)(n0 + srow) * 512 + k0 + sseg * 8;
            float4 p0 = *(const float4*)(src);
            float4 p1 = *(const float4*)(src + 4);
            bf16x8 v;
            v[0] = f2bf(p0.x); v[1] = f2bf(p0.y); v[2] = f2bf(p0.z); v[3] = f2bf(p0.w);
            v[4] = f2bf(p1.x); v[5] = f2bf(p1.y); v[6] = f2bf(p1.z); v[7] = f2bf(p1.w);
            *(bf16x8*)&sB[srow][sseg * 8] = v;
        }
        __syncthreads();
        bf16x8 a0 = *(bf16x8*)&sA[(mf + 0) * 16 + row16][kg * 8];
        bf16x8 a1 = *(bf16x8*)&sA[(mf + 1) * 16 + row16][kg * 8];
        #pragma unroll
        for (int j = 0; j < 4; ++j) {
            bf16x8 bv = *(bf16x8*)&sB[(nf + j) * 16 + row16][kg * 8];
            acc[0][j] = __builtin_amdgcn_mfma_f32_16x16x32_bf16(a0, bv, acc[0][j], 0, 0, 0);
            acc[1][j] = __builtin_amdgcn_mfma_f32_16x16x32_bf16(a1, bv, acc[1][j], 0, 0, 0);
        }
    }
}

__global__ __launch_bounds__(512) void k_embed(const float* __restrict__ x1,
                                               const float* __restrict__ x2,
                                               const float* __restrict__ w_e1,
                                               const float* __restrict__ b_e1,
                                               const float* __restrict__ w_e2,
                                               const float* __restrict__ b_e2,
                                               short* __restrict__ xb) {
    __shared__ short sA[128][40];
    __shared__ short sB[128][40];
    int bid = blockIdx.x;
    int mt = bid >> 1, nt = bid & 1;
    int m0 = mt * 128, n0 = nt * 128;
    int tid = threadIdx.x;
    int lane = tid & 63, w = tid >> 6;
    int mf = (w & 3) * 2;
    int nf = (w >> 2) * 4;
    int row16 = lane & 15, kg = lane >> 4;
    int srow = tid >> 2, sseg = tid & 3;

    f32x4 acc[2][4], keep[2][4];
    #pragma unroll
    for (int a = 0; a < 2; ++a)
        #pragma unroll
        for (int j = 0; j < 4; ++j) { acc[a][j] = {0.f, 0.f, 0.f, 0.f}; }

    gemm_pass(x1, w_e1, sA, sB, m0, n0, srow, sseg, mf, nf, row16, kg, acc);
    #pragma unroll
    for (int a = 0; a < 2; ++a)
        #pragma unroll
        for (int j = 0; j < 4; ++j) { keep[a][j] = acc[a][j]; acc[a][j] = {0.f, 0.f, 0.f, 0.f}; }
    gemm_pass(x2, w_e2, sA, sB, m0, n0, srow, sseg, mf, nf, row16, kg, acc);

    #pragma unroll
    for (int a = 0; a < 2; ++a) {
        int mbase = m0 + (mf + a) * 16 + kg * 4;
        #pragma unroll
        for (int j = 0; j < 4; ++j) {
            int n = n0 + (nf + j) * 16 + row16;
            float be1 = b_e1[n], be2 = b_e2[n];
            #pragma unroll
            for (int e = 0; e < 4; ++e) {
                float v1 = fmaxf(keep[a][j][e] + be1, 0.f);
                float v2 = fmaxf(acc[a][j][e] + be2, 0.f);
                xb[(size_t)(mbase + e) * 256 + n] = f2bf(v1 + v2);
            }
        }
    }
}

// ------------- aux: exact fp32 channel-0 of x2e (for cond), and xw = x . w_x ----
__global__ __launch_bounds__(256) void k_aux(const float* __restrict__ x2,
                                             const float* __restrict__ w_e2,
                                             const float* __restrict__ b_e2,
                                             const short* __restrict__ xb,
                                             const float* __restrict__ w_x,
                                             float* __restrict__ c0,
                                             float* __restrict__ xw) {
    int w = threadIdx.x >> 6, lane = threadIdx.x & 63;
    int m = blockIdx.x * 4 + w;
    const float* xr = x2 + (size_t)m * 512 + lane * 8;
    const float* wr = w_e2 + lane * 8;
    float s = 0.f;
    #pragma unroll
    for (int q = 0; q < 8; ++q) s += xr[q] * wr[q];
    #pragma unroll
    for (int o = 32; o; o >>= 1) s += __shfl_xor(s, o);
    float pre = s + b_e2[0];

    float t = 0.f;
    if (lane < 32) {
        const short* xbr = xb + (size_t)m * 256 + lane * 8;
        #pragma unroll
        for (int q = 0; q < 8; ++q) t += bf2f(xbr[q]) * w_x[lane * 8 + q];
    }
    #pragma unroll
    for (int o = 32; o; o >>= 1) t += __shfl_xor(t, o);
    if (lane == 0) { c0[m] = fmaxf(pre, 0.f); xw[m] = t; }
}

// ------------- aux2: cond bitmasks per batch + se = s@w_s^T + b_s --------------
__global__ __launch_bounds__(256) void k_aux2(const float* __restrict__ c0,
                                              const float* __restrict__ s_in,
                                              const float* __restrict__ w_s,
                                              const float* __restrict__ b_s,
                                              unsigned long long* __restrict__ condbits,
                                              float* __restrict__ se) {
    __shared__ float sS[64];
    int b = blockIdx.x;
    int t = threadIdx.x;
    if (t < 64) sS[t] = s_in[b * 64 + t];
    __syncthreads();
    float acc = b_s[t];
    const float* wr = w_s + t * 64;
    #pragma unroll 8
    for (int kk = 0; kk < 64; ++kk) acc += sS[kk] * wr[kk];
    se[(size_t)b * 256 + t] = acc;
    if (t == 0) {
        unsigned long long bits = 0;
        bool run = true;
        const float* cr = c0 + (size_t)b * 48;
        for (int i = 0; i < 48; ++i) {
            if (run) bits |= (1ull << i);
            run = run && (cr[i] == 0.0f);
        }
        condbits[b] = bits;
    }
}

// ---------------- helpers for the scan's register-double-buffered GEMM ---------
__device__ __forceinline__ void load8(bf16x8 (&dst)[8], const short* p) {
    #pragma unroll
    for (int s = 0; s < 8; ++s) dst[s] = *(const bf16x8*)(p + s * 32);
}
__device__ __forceinline__ void mfma8(const bf16x8 (&a)[8], const bf16x8 (&b)[8], f32x4& acc) {
    #pragma unroll
    for (int s = 0; s < 8; ++s) acc = __builtin_amdgcn_mfma_f32_16x16x32_bf16(a[s], b[s], acc, 0, 0, 0);
}

#define B2_BODY(J, ACC) { \
    float aj = __shfl(pv, (J)); \
    bf16x4 v = *(const bf16x4*)(xq + (size_t)(J) * 256); \
    ACC[0] += aj * bf2f(v.x); ACC[1] += aj * bf2f(v.y); \
    ACC[2] += aj * bf2f(v.z); ACC[3] += aj * bf2f(v.w); }

#define GRU1(RC, ZC, GC, NC, HQ, PQ) { \
    float rr = 1.f / (1.f + __expf(-(RC))); \
    float zz = 1.f / (1.f + __expf(-(ZC))); \
    float nn = 1.f - 2.f / (__expf(2.f * ((NC) + rr * (GC))) + 1.f); \
    float hp = (1.f - zz) * nn + zz * (HQ); \
    (HQ) = hp; (PQ) = f2bf(hp); }

// ------------- persistent scan: 32 blocks x 16 batches, 1024 thr (16 waves) ----
// Weight tiles: W1 has 51 (48 gates + 3 scores), W2 has 48. Wave w owns
// W1 tiles {w, 16+w, 32+w, 48+w(if w<3)} and W2 tiles {w, 16+w, 32+w},
// register double-buffered. Wave m owns batch m for softmax+ctx (B1+B2 fused).
__global__ __launch_bounds__(1024) void k_scan(const short* __restrict__ W1,
                                               const short* __restrict__ W2,
                                               const float* __restrict__ b_hh,
                                               const float* __restrict__ b_h,
                                               const float* __restrict__ b_ih,
                                               const short* __restrict__ xb,
                                               const float* __restrict__ xw,
                                               const unsigned long long* __restrict__ condbits,
                                               const float* __restrict__ se,
                                               const float* __restrict__ w_out,
                                               const float* __restrict__ b_out,
                                               float* __restrict__ out) {
    __shared__ short lA[16][264];   // bf16 operand (h, then ctx)
    __shared__ float lG[16][772];   // r|z|hn gates (0..767)
    __shared__ float lN[16][260];   // i_n
    __shared__ float lS[16][48];    // attention scores
    __shared__ float lXW[16][48];
    __shared__ unsigned long long lC[16];

    const int tid = threadIdx.x;
    const int w = tid >> 6, lane = tid & 63;
    const int row16 = lane & 15, kg = lane >> 4;
    const int b0 = blockIdx.x * 16;
    const int nw = w * 16 + row16;      // output col within a gate block
    const int dc4 = lane * 4;           // 4 dims owned in B2/D/epilogue
    const int T16 = 65536;              // 16 tiles * 4096 shorts

    // hoisted per-lane biases
    float biasA[4];
    biasA[0] = b_hh[nw]; biasA[1] = b_hh[256 + nw]; biasA[2] = b_hh[512 + nw];
    biasA[3] = (w < 3) ? b_h[nw] : 0.f;
    float biasC[3];
    biasC[0] = b_ih[nw]; biasC[1] = b_ih[256 + nw]; biasC[2] = b_ih[512 + nw];

    for (int t = tid; t < 16 * 48; t += 1024) {
        int m = t / 48, j = t - m * 48;
        lXW[m][j] = xw[(size_t)(b0 + m) * 48 + j];
    }
    if (tid < 16) lC[tid] = condbits[b0 + tid];
    if (tid < 528) {                     // zero FULL lA extent incl. padding
        bf16x8 z = {};
        ((bf16x8*)lA)[tid] = z;
    }
    __syncthreads();

    const size_t xbase = (size_t)b0 * 48 * 256;
    const short* xq = xb + xbase + (size_t)w * 12288 + dc4;

    // GRU state for (batch w, dims dc4..dc4+3) in registers
    float h0 = 0.f, h1 = 0.f, h2 = 0.f, h3 = 0.f;

    const short* W1p = W1 + (size_t)(w * 16 + row16) * 256 + kg * 8;
    const short* W2p = W2 + (size_t)(w * 16 + row16) * 256 + kg * 8;

    bf16x8 wA[8], wB[8];

    for (int i = 0; i < 48; ++i) {
        // ---- Phase A: gates + scores = h @ [w_hh|w_h]^T ----
        load8(wA, W1p);
        bf16x8 av[8];
        #pragma unroll
        for (int s = 0; s < 8; ++s) av[s] = *(const bf16x8*)&lA[row16][kg * 8 + s * 32];
        load8(wB, W1p + T16);
        {
            f32x4 acc = {0.f, 0.f, 0.f, 0.f};
            mfma8(av, wA, acc);
            #pragma unroll
            for (int e = 0; e < 4; ++e) lG[kg * 4 + e][nw] = acc[e] + biasA[0];
        }
        load8(wA, W1p + 2 * T16);
        {
            f32x4 acc = {0.f, 0.f, 0.f, 0.f};
            mfma8(av, wB, acc);
            #pragma unroll
            for (int e = 0; e < 4; ++e) lG[kg * 4 + e][256 + nw] = acc[e] + biasA[1];
        }
        if (w < 3) load8(wB, W1p + 3 * T16);
        else       load8(wB, W2p);
        {
            f32x4 acc = {0.f, 0.f, 0.f, 0.f};
            mfma8(av, wA, acc);
            #pragma unroll
            for (int e = 0; e < 4; ++e) lG[kg * 4 + e][512 + nw] = acc[e] + biasA[2];
        }
        if (w < 3) {
            f32x4 acc = {0.f, 0.f, 0.f, 0.f};
            mfma8(av, wB, acc);
            #pragma unroll
            for (int e = 0; e < 4; ++e) lS[kg * 4 + e][nw] = acc[e] + biasA[3];
            load8(wB, W2p);           // W2 tile w for Phase C
        }
        __syncthreads();

        // ---- B1+B2 fused: wave w owns batch w ----
        float pv;
        {
            float val = -3.0e38f;
            if (lane < 48) {
                val = lS[w][lane];
                bool cb = (lC[w] >> i) & 1ull;
                if (lane == i) val += lXW[w][i];
                else if (cb && lane < i) val += lXW[w][lane];
            }
            float mx = val;
            #pragma unroll
            for (int o = 32; o; o >>= 1) mx = fmaxf(mx, __shfl_xor(mx, o));
            float ex = (lane < 48) ? __expf(val - mx) : 0.f;
            float sm = ex;
            #pragma unroll
            for (int o = 32; o; o >>= 1) sm += __shfl_xor(sm, o);
            pv = ex / sm;
        }
        {
            float aE[4] = {0.f, 0.f, 0.f, 0.f};
            float aO[4] = {0.f, 0.f, 0.f, 0.f};
            int j = 0;
            #pragma unroll 4
            for (; j + 1 <= i; j += 2) { B2_BODY(j, aE); B2_BODY(j + 1, aO); }
            if (j <= i) B2_BODY(j, aE);
            bf16x4 o;
            o.x = f2bf(aE[0] + aO[0]); o.y = f2bf(aE[1] + aO[1]);
            o.z = f2bf(aE[2] + aO[2]); o.w = f2bf(aE[3] + aO[3]);
            *(bf16x4*)&lA[w][dc4] = o;
        }
        __syncthreads();

        // ---- Phase C: gi = ctx @ w_ih^T (wB holds W2 tile w) ----
        {
            bf16x8 cv[8];
            #pragma unroll
            for (int s = 0; s < 8; ++s) cv[s] = *(const bf16x8*)&lA[row16][kg * 8 + s * 32];
            load8(wA, W2p + T16);
            {
                f32x4 acc = {0.f, 0.f, 0.f, 0.f};
                mfma8(cv, wB, acc);
                #pragma unroll
                for (int e = 0; e < 4; ++e) lG[kg * 4 + e][nw] += acc[e] + biasC[0];
            }
            load8(wB, W2p + 2 * T16);
            {
                f32x4 acc = {0.f, 0.f, 0.f, 0.f};
                mfma8(cv, wA, acc);
                #pragma unroll
                for (int e = 0; e < 4; ++e) lG[kg * 4 + e][256 + nw] += acc[e] + biasC[1];
            }
            {
                f32x4 acc = {0.f, 0.f, 0.f, 0.f};
                mfma8(cv, wB, acc);
                #pragma unroll
                for (int e = 0; e < 4; ++e) lN[kg * 4 + e][nw] = acc[e] + biasC[2];
            }
        }
        __syncthreads();

        // ---- Phase D: GRU update (batch w, dims dc4..dc4+3) ----
        {
            float4 r4 = *(float4*)&lG[w][dc4];
            float4 z4 = *(float4*)&lG[w][256 + dc4];
            float4 g4 = *(float4*)&lG[w][512 + dc4];
            float4 n4 = *(float4*)&lN[w][dc4];
            bf16x4 packed;
            GRU1(r4.x, z4.x, g4.x, n4.x, h0, packed.x);
            GRU1(r4.y, z4.y, g4.y, n4.y, h1, packed.y);
            GRU1(r4.z, z4.z, g4.z, n4.z, h2, packed.z);
            GRU1(r4.w, z4.w, g4.w, n4.w, h3, packed.w);
            *(bf16x4*)&lA[w][dc4] = packed;
        }
        __syncthreads();
    }

    // epilogue: y = sigmoid((hF + se) . w_out + b_out), wave w -> batch w
    {
        float4 s4 = *(const float4*)&se[(size_t)(b0 + w) * 256 + dc4];
        float4 w4 = *(const float4*)&w_out[dc4];
        float p = (h0 + s4.x) * w4.x + (h1 + s4.y) * w4.y +
                  (h2 + s4.z) * w4.z + (h3 + s4.w) * w4.w;
        #pragma unroll
        for (int o = 32; o; o >>= 1) p += __shfl_xor(p, o);
        if (lane == 0) out[b0 + w] = 1.f / (1.f + __expf(-(p + b_out[0])));
    }
}

extern "C" void kernel_launch(void* const* d_in, const int* in_sizes, int n_in,
                              void* d_out, int out_size, void* d_ws, size_t ws_size,
                              hipStream_t stream) {
    const float* x1   = (const float*)d_in[0];
    const float* x2   = (const float*)d_in[1];
    const float* s    = (const float*)d_in[2];
    const float* w_e1 = (const float*)d_in[3];
    const float* b_e1 = (const float*)d_in[4];
    const float* w_e2 = (const float*)d_in[5];
    const float* b_e2 = (const float*)d_in[6];
    const float* w_s  = (const float*)d_in[7];
    const float* b_s  = (const float*)d_in[8];
    const float* w_x  = (const float*)d_in[9];
    const float* w_h  = (const float*)d_in[10];
    const float* b_h  = (const float*)d_in[11];
    const float* w_ih = (const float*)d_in[12];
    const float* w_hh = (const float*)d_in[13];
    const float* b_ih = (const float*)d_in[14];
    const float* b_hh = (const float*)d_in[15];
    const float* w_out = (const float*)d_in[16];
    const float* b_out = (const float*)d_in[17];
    float* out = (float*)d_out;

    char* ws = (char*)d_ws;
    size_t off = 0;
    auto alloc = [&](size_t bytes) -> void* {
        void* p = ws + off;
        off = (off + bytes + 255) & ~(size_t)255;
        return p;
    };
    short* xb = (short*)alloc((size_t)B_ * L_ * D_ * 2);
    short* W1 = (short*)alloc(896 * 256 * 2);   // 816 rows used; padded
    short* W2 = (short*)alloc(768 * 256 * 2);
    float* c0 = (float*)alloc((size_t)B_ * L_ * 4);
    float* xw = (float*)alloc((size_t)B_ * L_ * 4);
    unsigned long long* cb = (unsigned long long*)alloc(B_ * 8);
    float* se = (float*)alloc((size_t)B_ * D_ * 4);

    hipLaunchKernelGGL(k_prep, dim3((816 * 256 + 768 * 256) / 256), dim3(256), 0, stream,
                       w_hh, w_h, w_ih, W1, W2);
    hipLaunchKernelGGL(k_embed, dim3(384), dim3(512), 0, stream,
                       x1, x2, w_e1, b_e1, w_e2, b_e2, xb);
    hipLaunchKernelGGL(k_aux, dim3(6144), dim3(256), 0, stream,
                       x2, w_e2, b_e2, xb, w_x, c0, xw);
    hipLaunchKernelGGL(k_aux2, dim3(512), dim3(256), 0, stream,
                       c0, s, w_s, b_s, cb, se);
    hipLaunchKernelGGL(k_scan, dim3(32), dim3(1024), 0, stream,
                       W1, W2, b_hh, b_h, b_ih, xb, xw, cb, se, w_out, b_out, out);
}

// Round 7
// 1138.889 us; speedup vs baseline: 1.3479x; 1.3479x over previous
//
#include <hip/hip_runtime.h>
#include <stdint.h>

#define B_ 512
#define L_ 48
#define D_ 256

typedef __attribute__((ext_vector_type(8))) short bf16x8;
typedef __attribute__((ext_vector_type(4))) float f32x4;

__device__ __forceinline__ short f2bf(float f) {
    union { float f; unsigned u; } v; v.f = f;
    unsigned u = v.u;
    unsigned r = (u + 0x7FFFu + ((u >> 16) & 1u)) >> 16;
    return (short)r;
}
__device__ __forceinline__ float bf2f(short s) {
    union { unsigned u; float f; } v; v.u = ((unsigned)(unsigned short)s) << 16;
    return v.f;
}

// ---------------- weight prep: fp32 -> bf16, concat [w_hh;w_h] ----------------
__global__ __launch_bounds__(256) void k_prep(const float* __restrict__ w_hh,
                                              const float* __restrict__ w_h,
                                              const float* __restrict__ w_ih,
                                              short* __restrict__ W1,
                                              short* __restrict__ W2) {
    int t = blockIdx.x * 256 + threadIdx.x;
    const int N1 = 768 * 256;
    const int N1b = 816 * 256;
    if (t < N1) {
        W1[t] = f2bf(w_hh[t]);
    } else if (t < N1b) {
        W1[t] = f2bf(w_h[t - N1]);
    } else {
        int u = t - N1b;
        if (u < 768 * 256) W2[u] = f2bf(w_ih[u]);
    }
}

// ---------------- embedding GEMM: x = relu(x1@we1^T+b1) + relu(x2@we2^T+b2) ----
__device__ __forceinline__ void gemm_pass(const float* __restrict__ X,
                                          const float* __restrict__ W,
                                          short (*sA)[40], short (*sB)[40],
                                          int m0, int n0, int srow, int sseg,
                                          int mf, int nf, int row16, int kg,
                                          f32x4 (&acc)[2][4]) {
    for (int k0 = 0; k0 < 512; k0 += 32) {
        __syncthreads();
        {
            const float* src = X + (size_t)(m0 + srow) * 512 + k0 + sseg * 8;
            float4 p0 = *(const float4*)(src);
            float4 p1 = *(const float4*)(src + 4);
            bf16x8 v;
            v[0] = f2bf(p0.x); v[1] = f2bf(p0.y); v[2] = f2bf(p0.z); v[3] = f2bf(p0.w);
            v[4] = f2bf(p1.x); v[5] = f2bf(p1.y); v[6] = f2bf(p1.z); v[7] = f2bf(p1.w);
            *(bf16x8*)&sA[srow][sseg * 8] = v;
        }
        {
            const float* src = W + (size_t)(n0 + srow) * 512 + k0 + sseg * 8;
            float4 p0 = *(const float4*)(src);
            float4 p1 = *(const float4*)(src + 4);
            bf16x8 v;
            v[0] = f2bf(p0.x); v[1] = f2bf(p0.y); v[2] = f2bf(p0.z); v[3] = f2bf(p0.w);
            v[4] = f2bf(p1.x); v[5] = f2bf(p1.y); v[6] = f2bf(p1.z); v[7] = f2bf(p1.w);
            *(bf16x8*)&sB[srow][sseg * 8] = v;
        }
        __syncthreads();
        bf16x8 a0 = *(bf16x8*)&sA[(mf + 0) * 16 + row16][kg * 8];
        bf16x8 a1 = *(bf16x8*)&sA[(mf + 1) * 16 + row16][kg * 8];
        #pragma unroll
        for (int j = 0; j < 4; ++j) {
            bf16x8 bv = *(bf16x8*)&sB[(nf + j) * 16 + row16][kg * 8];
            acc[0][j] = __builtin_amdgcn_mfma_f32_16x16x32_bf16(a0, bv, acc[0][j], 0, 0, 0);
            acc[1][j] = __builtin_amdgcn_mfma_f32_16x16x32_bf16(a1, bv, acc[1][j], 0, 0, 0);
        }
    }
}

__global__ __launch_bounds__(512) void k_embed(const float* __restrict__ x1,
                                               const float* __restrict__ x2,
                                               const float* __restrict__ w_e1,
                                               const float* __restrict__ b_e1,
                                               const float* __restrict__ w_e2,
                                               const float* __restrict__ b_e2,
                                               short* __restrict__ xb) {
    __shared__ short sA[128][40];
    __shared__ short sB[128][40];
    int bid = blockIdx.x;
    int mt = bid >> 1, nt = bid & 1;
    int m0 = mt * 128, n0 = nt * 128;
    int tid = threadIdx.x;
    int lane = tid & 63, w = tid >> 6;
    int mf = (w & 3) * 2;
    int nf = (w >> 2) * 4;
    int row16 = lane & 15, kg = lane >> 4;
    int srow = tid >> 2, sseg = tid & 3;

    f32x4 acc[2][4], keep[2][4];
    #pragma unroll
    for (int a = 0; a < 2; ++a)
        #pragma unroll
        for (int j = 0; j < 4; ++j) { acc[a][j] = {0.f, 0.f, 0.f, 0.f}; }

    gemm_pass(x1, w_e1, sA, sB, m0, n0, srow, sseg, mf, nf, row16, kg, acc);
    #pragma unroll
    for (int a = 0; a < 2; ++a)
        #pragma unroll
        for (int j = 0; j < 4; ++j) { keep[a][j] = acc[a][j]; acc[a][j] = {0.f, 0.f, 0.f, 0.f}; }
    gemm_pass(x2, w_e2, sA, sB, m0, n0, srow, sseg, mf, nf, row16, kg, acc);

    #pragma unroll
    for (int a = 0; a < 2; ++a) {
        int mbase = m0 + (mf + a) * 16 + kg * 4;
        #pragma unroll
        for (int j = 0; j < 4; ++j) {
            int n = n0 + (nf + j) * 16 + row16;
            float be1 = b_e1[n], be2 = b_e2[n];
            #pragma unroll
            for (int e = 0; e < 4; ++e) {
                float v1 = fmaxf(keep[a][j][e] + be1, 0.f);
                float v2 = fmaxf(acc[a][j][e] + be2, 0.f);
                xb[(size_t)(mbase + e) * 256 + n] = f2bf(v1 + v2);
            }
        }
    }
}

// ------------- aux: exact fp32 channel-0 of x2e (for cond), and xw = x . w_x ----
__global__ __launch_bounds__(256) void k_aux(const float* __restrict__ x2,
                                             const float* __restrict__ w_e2,
                                             const float* __restrict__ b_e2,
                                             const short* __restrict__ xb,
                                             const float* __restrict__ w_x,
                                             float* __restrict__ c0,
                                             float* __restrict__ xw) {
    int w = threadIdx.x >> 6, lane = threadIdx.x & 63;
    int m = blockIdx.x * 4 + w;
    const float* xr = x2 + (size_t)m * 512 + lane * 8;
    const float* wr = w_e2 + lane * 8;
    float s = 0.f;
    #pragma unroll
    for (int q = 0; q < 8; ++q) s += xr[q] * wr[q];
    #pragma unroll
    for (int o = 32; o; o >>= 1) s += __shfl_xor(s, o);
    float pre = s + b_e2[0];

    float t = 0.f;
    if (lane < 32) {
        const short* xbr = xb + (size_t)m * 256 + lane * 8;
        #pragma unroll
        for (int q = 0; q < 8; ++q) t += bf2f(xbr[q]) * w_x[lane * 8 + q];
    }
    #pragma unroll
    for (int o = 32; o; o >>= 1) t += __shfl_xor(t, o);
    if (lane == 0) { c0[m] = fmaxf(pre, 0.f); xw[m] = t; }
}

// ------------- aux2: cond bitmasks per batch + se = s@w_s^T + b_s --------------
__global__ __launch_bounds__(256) void k_aux2(const float* __restrict__ c0,
                                              const float* __restrict__ s_in,
                                              const float* __restrict__ w_s,
                                              const float* __restrict__ b_s,
                                              unsigned long long* __restrict__ condbits,
                                              float* __restrict__ se) {
    __shared__ float sS[64];
    int b = blockIdx.x;
    int t = threadIdx.x;
    if (t < 64) sS[t] = s_in[b * 64 + t];
    __syncthreads();
    float acc = b_s[t];
    const float* wr = w_s + t * 64;
    #pragma unroll 8
    for (int kk = 0; kk < 64; ++kk) acc += sS[kk] * wr[kk];
    se[(size_t)b * 256 + t] = acc;
    if (t == 0) {
        unsigned long long bits = 0;
        bool run = true;
        const float* cr = c0 + (size_t)b * 48;
        for (int i = 0; i < 48; ++i) {
            if (run) bits |= (1ull << i);
            run = run && (cr[i] == 0.0f);
        }
        condbits[b] = bits;
    }
}

// ---------------- helpers for the scan's register-double-buffered GEMM ---------
__device__ __forceinline__ void load8(bf16x8 (&dst)[8], const short* p) {
    #pragma unroll
    for (int s = 0; s < 8; ++s) dst[s] = *(const bf16x8*)(p + s * 32);
}
// A-fragment read from LDS fused into the MFMA chain (no persistent av[] regs)
__device__ __forceinline__ void mfma8_lds(const short* ap, const bf16x8 (&b)[8], f32x4& acc) {
    #pragma unroll
    for (int s = 0; s < 8; ++s) {
        bf16x8 a = *(const bf16x8*)(ap + s * 32);
        acc = __builtin_amdgcn_mfma_f32_16x16x32_bf16(a, b[s], acc, 0, 0, 0);
    }
}

// ---------------- persistent scan: 32 blocks x 16 batches, 48 steps ------------
// Weights streamed from L2, register double-buffered (wA/wB only); A-operand
// and biases come from LDS to keep VGPR live-set under 128 (no spill).
__global__ __launch_bounds__(512) void k_scan(const short* __restrict__ W1,
                                              const short* __restrict__ W2,
                                              const float* __restrict__ b_hh,
                                              const float* __restrict__ b_h,
                                              const float* __restrict__ b_ih,
                                              const short* __restrict__ xb,
                                              const float* __restrict__ xw,
                                              const unsigned long long* __restrict__ condbits,
                                              const float* __restrict__ se,
                                              const float* __restrict__ w_out,
                                              const float* __restrict__ b_out,
                                              float* __restrict__ out) {
    __shared__ short lA[16][264];   // bf16 operand (h, then ctx)
    __shared__ float lG[16][772];   // r|z|hn gates (0..767)
    __shared__ float lS[16][52];    // attention scores
    __shared__ float lN[16][260];   // i_n
    __shared__ float lT[16][48];    // softmax a
    __shared__ float lXW[16][48];
    __shared__ float lbA[816];      // b_hh | b_h  (bias by output col)
    __shared__ float lbC[768];      // b_ih
    __shared__ unsigned long long lC[16];

    const int tid = threadIdx.x;
    const int w = tid >> 6, lane = tid & 63;
    const int row16 = lane & 15, kg = lane >> 4;
    const int b0 = blockIdx.x * 16;

    for (int t = tid; t < 816; t += 512) lbA[t] = (t < 768) ? b_hh[t] : b_h[t - 768];
    for (int t = tid; t < 768; t += 512) lbC[t] = b_ih[t];
    for (int t = tid; t < 16 * 48; t += 512) {
        int m = t / 48, j = t - m * 48;
        lXW[m][j] = xw[(size_t)(b0 + m) * 48 + j];
    }
    if (tid < 16) lC[tid] = condbits[b0 + tid];
    // zero the FULL lA extent (16*264 shorts = 528 bf16x8 chunks)
    for (int t = tid; t < 528; t += 512) {
        bf16x8 z = {};
        ((bf16x8*)lA)[t] = z;
    }
    __syncthreads();

    const size_t xbase = (size_t)b0 * 48 * 256;
    const int mi = tid >> 5, dc8 = (tid & 31) * 8;
    const short* xr = xb + xbase + (size_t)mi * 12288 + dc8;
    const short* ap = &lA[row16][kg * 8];

    // GRU state for (batch mi, dims dc8..dc8+7) lives in registers
    float hreg[8];
    #pragma unroll
    for (int q = 0; q < 8; ++q) hreg[q] = 0.f;

    // per-lane weight base pointers (tile u of a phase = +u*32768 shorts)
    const short* W1p = W1 + (size_t)(w * 16 + row16) * 256 + kg * 8;
    const short* W2p = W2 + (size_t)(w * 16 + row16) * 256 + kg * 8;

    bf16x8 wA[8], wB[8];

    for (int i = 0; i < 48; ++i) {
        // ---- Phase A: [gh | scores] = h @ [w_hh|w_h]^T, 7 tiles, dbuf'd ----
        load8(wA, W1p);
        #pragma unroll
        for (int u = 0; u < 7; ++u) {
            const int t = u * 8 + w;
            if (u < 6) {               // prefetch next tile (u=5 may hit pad rows)
                if ((u & 1) == 0) load8(wB, W1p + (u + 1) * 32768);
                else              load8(wA, W1p + (u + 1) * 32768);
            } else {                   // u==6: prefetch first C tile (W2, tile w)
                load8(wB, W2p);
            }
            if (t < 51) {
                f32x4 acc = {0.f, 0.f, 0.f, 0.f};
                if ((u & 1) == 0) mfma8_lds(ap, wA, acc);
                else              mfma8_lds(ap, wB, acc);
                const int n = t * 16 + row16;
                const float bA = lbA[n];
                if (t < 48) {
                    #pragma unroll
                    for (int e = 0; e < 4; ++e) lG[kg * 4 + e][n] = acc[e] + bA;
                } else {
                    #pragma unroll
                    for (int e = 0; e < 4; ++e) lS[kg * 4 + e][n - 768] = acc[e] + bA;
                }
            }
        }
        __syncthreads();

        // ---- B1: softmax over 48 positions (wave w -> batches 2w, 2w+1) ----
        #pragma unroll
        for (int rep = 0; rep < 2; ++rep) {
            int m = w * 2 + rep;
            float val = -3.0e38f;
            if (lane < 48) {
                val = lS[m][lane];
                bool cb = (lC[m] >> i) & 1ull;
                if (lane == i) val += lXW[m][i];
                else if (cb && lane < i) val += lXW[m][lane];
            }
            float mx = val;
            #pragma unroll
            for (int o = 32; o; o >>= 1) mx = fmaxf(mx, __shfl_xor(mx, o));
            float ex = (lane < 48) ? __expf(val - mx) : 0.f;
            float sm = ex;
            #pragma unroll
            for (int o = 32; o; o >>= 1) sm += __shfl_xor(sm, o);
            if (lane < 48) lT[m][lane] = ex / sm;
        }
        __syncthreads();

        // ---- B2: ctx = sum_{j<=i} a_j * x[b,j,:], 8 dims per thread ----
        {
            float acc[8];
            #pragma unroll
            for (int q = 0; q < 8; ++q) acc[q] = 0.f;
            #pragma unroll 4
            for (int j = 0; j <= i; ++j) {
                float aj = lT[mi][j];
                bf16x8 v = *(const bf16x8*)(xr + j * 256);
                #pragma unroll
                for (int q = 0; q < 8; ++q) acc[q] += aj * bf2f(v[q]);
            }
            bf16x8 o;
            #pragma unroll
            for (int q = 0; q < 8; ++q) o[q] = f2bf(acc[q]);
            *(bf16x8*)&lA[mi][dc8] = o;
        }
        __syncthreads();

        // ---- Phase C: gi = ctx @ w_ih^T, 6 tiles, dbuf'd (starts in wB) ----
        {
            #pragma unroll
            for (int u = 0; u < 6; ++u) {
                const int t = u * 8 + w;
                if (u < 5) {
                    if ((u & 1) == 0) load8(wA, W2p + (u + 1) * 32768);
                    else              load8(wB, W2p + (u + 1) * 32768);
                }
                f32x4 acc = {0.f, 0.f, 0.f, 0.f};
                if ((u & 1) == 0) mfma8_lds(ap, wB, acc);
                else              mfma8_lds(ap, wA, acc);
                const int n = t * 16 + row16;
                const float bC = lbC[n];
                if (t < 32) {
                    #pragma unroll
                    for (int e = 0; e < 4; ++e) lG[kg * 4 + e][n] += acc[e] + bC;
                } else {
                    #pragma unroll
                    for (int e = 0; e < 4; ++e) lN[kg * 4 + e][n - 512] = acc[e] + bC;
                }
            }
        }
        __syncthreads();

        // ---- Phase D: GRU update (state in registers) ----
        {
            bf16x8 packed;
            #pragma unroll
            for (int q = 0; q < 8; ++q) {
                int d = dc8 + q;
                float r = 1.f / (1.f + __expf(-lG[mi][d]));
                float z = 1.f / (1.f + __expf(-lG[mi][256 + d]));
                float narg = lN[mi][d] + r * lG[mi][512 + d];
                float nn = 1.f - 2.f / (__expf(2.f * narg) + 1.f);   // tanh
                float hp = (1.f - z) * nn + z * hreg[q];
                hreg[q] = hp;
                packed[q] = f2bf(hp);
            }
            *(bf16x8*)&lA[mi][dc8] = packed;
        }
        __syncthreads();
    }

    // epilogue: y = sigmoid((hF + se) . w_out + b_out), 32-lane reduce per batch
    {
        const float* sep = se + (size_t)(b0 + mi) * 256 + dc8;
        const float* wop = w_out + dc8;
        float p = 0.f;
        #pragma unroll
        for (int q = 0; q < 8; ++q) p += (hreg[q] + sep[q]) * wop[q];
        #pragma unroll
        for (int o = 16; o; o >>= 1) p += __shfl_xor(p, o);
        if ((tid & 31) == 0) out[b0 + mi] = 1.f / (1.f + __expf(-(p + b_out[0])));
    }
}

extern "C" void kernel_launch(void* const* d_in, const int* in_sizes, int n_in,
                              void* d_out, int out_size, void* d_ws, size_t ws_size,
                              hipStream_t stream) {
    const float* x1   = (const float*)d_in[0];
    const float* x2   = (const float*)d_in[1];
    const float* s    = (const float*)d_in[2];
    const float* w_e1 = (const float*)d_in[3];
    const float* b_e1 = (const float*)d_in[4];
    const float* w_e2 = (const float*)d_in[5];
    const float* b_e2 = (const float*)d_in[6];
    const float* w_s  = (const float*)d_in[7];
    const float* b_s  = (const float*)d_in[8];
    const float* w_x  = (const float*)d_in[9];
    const float* w_h  = (const float*)d_in[10];
    const float* b_h  = (const float*)d_in[11];
    const float* w_ih = (const float*)d_in[12];
    const float* w_hh = (const float*)d_in[13];
    const float* b_ih = (const float*)d_in[14];
    const float* b_hh = (const float*)d_in[15];
    const float* w_out = (const float*)d_in[16];
    const float* b_out = (const float*)d_in[17];
    float* out = (float*)d_out;

    char* ws = (char*)d_ws;
    size_t off = 0;
    auto alloc = [&](size_t bytes) -> void* {
        void* p = ws + off;
        off = (off + bytes + 255) & ~(size_t)255;
        return p;
    };
    short* xb = (short*)alloc((size_t)B_ * L_ * D_ * 2);
    short* W1 = (short*)alloc(896 * 256 * 2);   // 816 rows used; padded
    short* W2 = (short*)alloc(768 * 256 * 2);
    float* c0 = (float*)alloc((size_t)B_ * L_ * 4);
    float* xw = (float*)alloc((size_t)B_ * L_ * 4);
    unsigned long long* cb = (unsigned long long*)alloc(B_ * 8);
    float* se = (float*)alloc((size_t)B_ * D_ * 4);

    hipLaunchKernelGGL(k_prep, dim3((816 * 256 + 768 * 256) / 256), dim3(256), 0, stream,
                       w_hh, w_h, w_ih, W1, W2);
    hipLaunchKernelGGL(k_embed, dim3(384), dim3(512), 0, stream,
                       x1, x2, w_e1, b_e1, w_e2, b_e2, xb);
    hipLaunchKernelGGL(k_aux, dim3(6144), dim3(256), 0, stream,
                       x2, w_e2, b_e2, xb, w_x, c0, xw);
    hipLaunchKernelGGL(k_aux2, dim3(512), dim3(256), 0, stream,
                       c0, s, w_s, b_s, cb, se);
    hipLaunchKernelGGL(k_scan, dim3(32), dim3(512), 0, stream,
                       W1, W2, b_hh, b_h, b_ih, xb, xw, cb, se, w_out, b_out, out);
}

// Round 8
// 606.436 us; speedup vs baseline: 2.5315x; 1.8780x over previous
//
#include <hip/hip_runtime.h>
#include <stdint.h>

#define B_ 512
#define L_ 48
#define D_ 256

typedef __attribute__((ext_vector_type(8))) short bf16x8;
typedef __attribute__((ext_vector_type(4))) float f32x4;
typedef __attribute__((ext_vector_type(4))) int i32x4;

__device__ __forceinline__ short f2bf(float f) {
    union { float f; unsigned u; } v; v.f = f;
    unsigned u = v.u;
    unsigned r = (u + 0x7FFFu + ((u >> 16) & 1u)) >> 16;
    return (short)r;
}
__device__ __forceinline__ float bf2f(short s) {
    union { unsigned u; float f; } v; v.u = ((unsigned)(unsigned short)s) << 16;
    return v.f;
}

// -------- weight prep: per-row symmetric i8 quant of [w_hh;w_h] and w_ih -------
// W1q rows 0..767 = w_hh, 768..815 = w_h (pad to 896 rows). W2q = w_ih.
// qA[n] = rowmax/(127*127)  (h scale 127);  qC[n] = rowmax*8/(127*127) (ctx scale 127/8).
__global__ __launch_bounds__(256) void k_prep(const float* __restrict__ w_hh,
                                              const float* __restrict__ w_h,
                                              const float* __restrict__ w_ih,
                                              signed char* __restrict__ W1q,
                                              signed char* __restrict__ W2q,
                                              float* __restrict__ qA,
                                              float* __restrict__ qC) {
    int w = threadIdx.x >> 6, lane = threadIdx.x & 63;
    int R = blockIdx.x * 4 + w;
    if (R >= 1584) return;
    const float* src;
    signed char* dst;
    bool isA = (R < 816);
    if (R < 768)      { src = w_hh + (size_t)R * 256;         dst = W1q + (size_t)R * 256; }
    else if (R < 816) { src = w_h + (size_t)(R - 768) * 256;  dst = W1q + (size_t)R * 256; }
    else              { src = w_ih + (size_t)(R - 816) * 256; dst = W2q + (size_t)(R - 816) * 256; }
    float4 v = *(const float4*)(src + lane * 4);
    float m = fmaxf(fmaxf(fabsf(v.x), fabsf(v.y)), fmaxf(fabsf(v.z), fabsf(v.w)));
    #pragma unroll
    for (int o = 32; o; o >>= 1) m = fmaxf(m, __shfl_xor(m, o));
    float sc = (m > 0.f) ? 127.f / m : 0.f;
    int b0 = __float2int_rn(v.x * sc), b1 = __float2int_rn(v.y * sc);
    int b2 = __float2int_rn(v.z * sc), b3 = __float2int_rn(v.w * sc);
    unsigned word = (unsigned)(b0 & 255) | ((unsigned)(b1 & 255) << 8) |
                    ((unsigned)(b2 & 255) << 16) | ((unsigned)(b3 & 255) << 24);
    ((unsigned*)dst)[lane] = word;
    if (lane == 0) {
        if (isA) qA[R] = m / (127.f * 127.f);
        else     qC[R - 816] = m * 8.f / (127.f * 127.f);
    }
}

// ---------------- embedding GEMM: x = relu(x1@we1^T+b1) + relu(x2@we2^T+b2) ----
__device__ __forceinline__ void gemm_pass(const float* __restrict__ X,
                                          const float* __restrict__ W,
                                          short (*sA)[40], short (*sB)[40],
                                          int m0, int n0, int srow, int sseg,
                                          int mf, int nf, int row16, int kg,
                                          f32x4 (&acc)[2][4]) {
    for (int k0 = 0; k0 < 512; k0 += 32) {
        __syncthreads();
        {
            const float* src = X + (size_t)(m0 + srow) * 512 + k0 + sseg * 8;
            float4 p0 = *(const float4*)(src);
            float4 p1 = *(const float4*)(src + 4);
            bf16x8 v;
            v[0] = f2bf(p0.x); v[1] = f2bf(p0.y); v[2] = f2bf(p0.z); v[3] = f2bf(p0.w);
            v[4] = f2bf(p1.x); v[5] = f2bf(p1.y); v[6] = f2bf(p1.z); v[7] = f2bf(p1.w);
            *(bf16x8*)&sA[srow][sseg * 8] = v;
        }
        {
            const float* src = W + (size_t)(n0 + srow) * 512 + k0 + sseg * 8;
            float4 p0 = *(const float4*)(src);
            float4 p1 = *(const float4*)(src + 4);
            bf16x8 v;
            v[0] = f2bf(p0.x); v[1] = f2bf(p0.y); v[2] = f2bf(p0.z); v[3] = f2bf(p0.w);
            v[4] = f2bf(p1.x); v[5] = f2bf(p1.y); v[6] = f2bf(p1.z); v[7] = f2bf(p1.w);
            *(bf16x8*)&sB[srow][sseg * 8] = v;
        }
        __syncthreads();
        bf16x8 a0 = *(bf16x8*)&sA[(mf + 0) * 16 + row16][kg * 8];
        bf16x8 a1 = *(bf16x8*)&sA[(mf + 1) * 16 + row16][kg * 8];
        #pragma unroll
        for (int j = 0; j < 4; ++j) {
            bf16x8 bv = *(bf16x8*)&sB[(nf + j) * 16 + row16][kg * 8];
            acc[0][j] = __builtin_amdgcn_mfma_f32_16x16x32_bf16(a0, bv, acc[0][j], 0, 0, 0);
            acc[1][j] = __builtin_amdgcn_mfma_f32_16x16x32_bf16(a1, bv, acc[1][j], 0, 0, 0);
        }
    }
}

__global__ __launch_bounds__(512) void k_embed(const float* __restrict__ x1,
                                               const float* __restrict__ x2,
                                               const float* __restrict__ w_e1,
                                               const float* __restrict__ b_e1,
                                               const float* __restrict__ w_e2,
                                               const float* __restrict__ b_e2,
                                               short* __restrict__ xb) {
    __shared__ short sA[128][40];
    __shared__ short sB[128][40];
    int bid = blockIdx.x;
    int mt = bid >> 1, nt = bid & 1;
    int m0 = mt * 128, n0 = nt * 128;
    int tid = threadIdx.x;
    int lane = tid & 63, w = tid >> 6;
    int mf = (w & 3) * 2;
    int nf = (w >> 2) * 4;
    int row16 = lane & 15, kg = lane >> 4;
    int srow = tid >> 2, sseg = tid & 3;

    f32x4 acc[2][4], keep[2][4];
    #pragma unroll
    for (int a = 0; a < 2; ++a)
        #pragma unroll
        for (int j = 0; j < 4; ++j) { acc[a][j] = {0.f, 0.f, 0.f, 0.f}; }

    gemm_pass(x1, w_e1, sA, sB, m0, n0, srow, sseg, mf, nf, row16, kg, acc);
    #pragma unroll
    for (int a = 0; a < 2; ++a)
        #pragma unroll
        for (int j = 0; j < 4; ++j) { keep[a][j] = acc[a][j]; acc[a][j] = {0.f, 0.f, 0.f, 0.f}; }
    gemm_pass(x2, w_e2, sA, sB, m0, n0, srow, sseg, mf, nf, row16, kg, acc);

    #pragma unroll
    for (int a = 0; a < 2; ++a) {
        int mbase = m0 + (mf + a) * 16 + kg * 4;
        #pragma unroll
        for (int j = 0; j < 4; ++j) {
            int n = n0 + (nf + j) * 16 + row16;
            float be1 = b_e1[n], be2 = b_e2[n];
            #pragma unroll
            for (int e = 0; e < 4; ++e) {
                float v1 = fmaxf(keep[a][j][e] + be1, 0.f);
                float v2 = fmaxf(acc[a][j][e] + be2, 0.f);
                xb[(size_t)(mbase + e) * 256 + n] = f2bf(v1 + v2);
            }
        }
    }
}

// ------------- aux: exact fp32 channel-0 of x2e (for cond), and xw = x . w_x ----
__global__ __launch_bounds__(256) void k_aux(const float* __restrict__ x2,
                                             const float* __restrict__ w_e2,
                                             const float* __restrict__ b_e2,
                                             const short* __restrict__ xb,
                                             const float* __restrict__ w_x,
                                             float* __restrict__ c0,
                                             float* __restrict__ xw) {
    int w = threadIdx.x >> 6, lane = threadIdx.x & 63;
    int m = blockIdx.x * 4 + w;
    const float* xr = x2 + (size_t)m * 512 + lane * 8;
    const float* wr = w_e2 + lane * 8;
    float s = 0.f;
    #pragma unroll
    for (int q = 0; q < 8; ++q) s += xr[q] * wr[q];
    #pragma unroll
    for (int o = 32; o; o >>= 1) s += __shfl_xor(s, o);
    float pre = s + b_e2[0];

    float t = 0.f;
    if (lane < 32) {
        const short* xbr = xb + (size_t)m * 256 + lane * 8;
        #pragma unroll
        for (int q = 0; q < 8; ++q) t += bf2f(xbr[q]) * w_x[lane * 8 + q];
    }
    #pragma unroll
    for (int o = 32; o; o >>= 1) t += __shfl_xor(t, o);
    if (lane == 0) { c0[m] = fmaxf(pre, 0.f); xw[m] = t; }
}

// ------------- aux2: cond bitmasks per batch + se = s@w_s^T + b_s --------------
__global__ __launch_bounds__(256) void k_aux2(const float* __restrict__ c0,
                                              const float* __restrict__ s_in,
                                              const float* __restrict__ w_s,
                                              const float* __restrict__ b_s,
                                              unsigned long long* __restrict__ condbits,
                                              float* __restrict__ se) {
    __shared__ float sS[64];
    int b = blockIdx.x;
    int t = threadIdx.x;
    if (t < 64) sS[t] = s_in[b * 64 + t];
    __syncthreads();
    float acc = b_s[t];
    const float* wr = w_s + t * 64;
    #pragma unroll 8
    for (int kk = 0; kk < 64; ++kk) acc += sS[kk] * wr[kk];
    se[(size_t)b * 256 + t] = acc;
    if (t == 0) {
        unsigned long long bits = 0;
        bool run = true;
        const float* cr = c0 + (size_t)b * 48;
        for (int i = 0; i < 48; ++i) {
            if (run) bits |= (1ull << i);
            run = run && (cr[i] == 0.0f);
        }
        condbits[b] = bits;
    }
}

// ---------------- i8 GEMM helpers (register double-buffered weights) -----------
__device__ __forceinline__ void load4w(i32x4 (&dst)[4], const signed char* p) {
    #pragma unroll
    for (int s = 0; s < 4; ++s) dst[s] = *(const i32x4*)(p + s * 64);
}
__device__ __forceinline__ void mfma4i(const signed char* ap, const i32x4 (&b)[4], i32x4& acc) {
    #pragma unroll
    for (int s = 0; s < 4; ++s) {
        i32x4 a = *(const i32x4*)(ap + s * 64);
        acc = __builtin_amdgcn_mfma_i32_16x16x64_i8(a, b[s], acc, 0, 0, 0);
    }
}

// ---------------- persistent scan: 32 blocks x 16 batches, 48 steps ------------
// i8 weights (half the stream of bf16), i8 h/ctx operands, exact i32 accum,
// per-row float dequant. fp32 GRU state in registers.
__global__ __launch_bounds__(512) void k_scan(const signed char* __restrict__ W1q,
                                              const signed char* __restrict__ W2q,
                                              const float* __restrict__ qAg,
                                              const float* __restrict__ qCg,
                                              const float* __restrict__ b_hh,
                                              const float* __restrict__ b_h,
                                              const float* __restrict__ b_ih,
                                              const short* __restrict__ xb,
                                              const float* __restrict__ xw,
                                              const unsigned long long* __restrict__ condbits,
                                              const float* __restrict__ se,
                                              const float* __restrict__ w_out,
                                              const float* __restrict__ b_out,
                                              float* __restrict__ out) {
    __shared__ i32x4 lA8v[16 * 17];   // [16][272] i8 operand (h, then ctx)
    __shared__ float lG[16][772];     // r|z|hn gates
    __shared__ float lS[16][52];      // attention scores
    __shared__ float lN[16][260];     // i_n
    __shared__ float lT[16][48];      // softmax a
    __shared__ float lXW[16][48];
    __shared__ float lbA[816], lqA[816], lbC[768], lqC[768];
    __shared__ unsigned long long lC[16];
    signed char* lA8 = (signed char*)lA8v;

    const int tid = threadIdx.x;
    const int w = tid >> 6, lane = tid & 63;
    const int row16 = lane & 15, kg = lane >> 4;
    const int b0 = blockIdx.x * 16;
    const float CS = 127.f / 8.f;     // ctx quant scale (ctx in [0, ~7.5])

    for (int t = tid; t < 816; t += 512) {
        lbA[t] = (t < 768) ? b_hh[t] : b_h[t - 768];
        lqA[t] = qAg[t];
    }
    for (int t = tid; t < 768; t += 512) { lbC[t] = b_ih[t]; lqC[t] = qCg[t]; }
    for (int t = tid; t < 16 * 48; t += 512) {
        int m = t / 48, j = t - m * 48;
        lXW[m][j] = xw[(size_t)(b0 + m) * 48 + j];
    }
    if (tid < 16) lC[tid] = condbits[b0 + tid];
    if (tid < 16 * 17) lA8v[tid] = (i32x4){0, 0, 0, 0};   // h(0) = 0
    __syncthreads();

    const size_t xbase = (size_t)b0 * 48 * 256;
    const int mi = tid >> 5, dc8 = (tid & 31) * 8;
    const short* xr = xb + xbase + (size_t)mi * 12288 + dc8;
    const signed char* ap = lA8 + row16 * 272 + kg * 16;

    // GRU state for (batch mi, dims dc8..dc8+7) in registers
    float hreg[8];
    #pragma unroll
    for (int q = 0; q < 8; ++q) hreg[q] = 0.f;

    // per-lane weight base pointers (tile u = +u*4096 bytes; wave tile stride 8*4096)
    const signed char* W1p = W1q + (size_t)(w * 16 + row16) * 256 + kg * 16;
    const signed char* W2p = W2q + (size_t)(w * 16 + row16) * 256 + kg * 16;

    i32x4 wA[4], wB[4];

    for (int i = 0; i < 48; ++i) {
        // ---- Phase A: [gh | scores] = h @ [w_hh|w_h]^T, 7 tiles, dbuf'd ----
        load4w(wA, W1p);
        #pragma unroll
        for (int u = 0; u < 7; ++u) {
            const int t = u * 8 + w;
            if (u < 6) {               // prefetch next tile (u=5 may hit pad rows)
                if ((u & 1) == 0) load4w(wB, W1p + (u + 1) * 32768);
                else              load4w(wA, W1p + (u + 1) * 32768);
            } else {                   // u==6: prefetch first C tile (W2, tile w)
                load4w(wB, W2p);
            }
            if (t < 51) {
                i32x4 acc = {0, 0, 0, 0};
                if ((u & 1) == 0) mfma4i(ap, wA, acc);
                else              mfma4i(ap, wB, acc);
                const int n = t * 16 + row16;
                const float q = lqA[n], bA = lbA[n];
                if (t < 48) {
                    #pragma unroll
                    for (int e = 0; e < 4; ++e) lG[kg * 4 + e][n] = (float)acc[e] * q + bA;
                } else {
                    #pragma unroll
                    for (int e = 0; e < 4; ++e) lS[kg * 4 + e][n - 768] = (float)acc[e] * q + bA;
                }
            }
        }
        __syncthreads();

        // ---- B1: softmax over 48 positions (wave w -> batches 2w, 2w+1) ----
        #pragma unroll
        for (int rep = 0; rep < 2; ++rep) {
            int m = w * 2 + rep;
            float val = -3.0e38f;
            if (lane < 48) {
                val = lS[m][lane];
                bool cb = (lC[m] >> i) & 1ull;
                if (lane == i) val += lXW[m][i];
                else if (cb && lane < i) val += lXW[m][lane];
            }
            float mx = val;
            #pragma unroll
            for (int o = 32; o; o >>= 1) mx = fmaxf(mx, __shfl_xor(mx, o));
            float ex = (lane < 48) ? __expf(val - mx) : 0.f;
            float sm = ex;
            #pragma unroll
            for (int o = 32; o; o >>= 1) sm += __shfl_xor(sm, o);
            if (lane < 48) lT[m][lane] = ex / sm;
        }
        __syncthreads();

        // ---- B2: ctx = sum_{j<=i} a_j * x[b,j,:], 8 dims/thread, publish i8 ----
        {
            float acc[8];
            #pragma unroll
            for (int q = 0; q < 8; ++q) acc[q] = 0.f;
            #pragma unroll 4
            for (int j = 0; j <= i; ++j) {
                float aj = lT[mi][j];
                bf16x8 v = *(const bf16x8*)(xr + j * 256);
                #pragma unroll
                for (int q = 0; q < 8; ++q) acc[q] += aj * bf2f(v[q]);
            }
            union { signed char c[8]; int2 v2; } pk;
            #pragma unroll
            for (int q = 0; q < 8; ++q)
                pk.c[q] = (signed char)__float2int_rn(fminf(fmaxf(acc[q] * CS, -127.f), 127.f));
            *(int2*)(lA8 + mi * 272 + dc8) = pk.v2;
        }
        __syncthreads();

        // ---- Phase C: gi = ctx @ w_ih^T, 6 tiles, dbuf'd (starts in wB) ----
        {
            #pragma unroll
            for (int u = 0; u < 6; ++u) {
                const int t = u * 8 + w;
                if (u < 5) {
                    if ((u & 1) == 0) load4w(wA, W2p + (u + 1) * 32768);
                    else              load4w(wB, W2p + (u + 1) * 32768);
                }
                i32x4 acc = {0, 0, 0, 0};
                if ((u & 1) == 0) mfma4i(ap, wB, acc);
                else              mfma4i(ap, wA, acc);
                const int n = t * 16 + row16;
                const float q = lqC[n], bC = lbC[n];
                if (t < 32) {
                    #pragma unroll
                    for (int e = 0; e < 4; ++e) lG[kg * 4 + e][n] += (float)acc[e] * q + bC;
                } else {
                    #pragma unroll
                    for (int e = 0; e < 4; ++e) lN[kg * 4 + e][n - 512] = (float)acc[e] * q + bC;
                }
            }
        }
        __syncthreads();

        // ---- Phase D: GRU update (fp32 state in regs), publish h as i8 ----
        {
            union { signed char c[8]; int2 v2; } pk;
            #pragma unroll
            for (int q = 0; q < 8; ++q) {
                int d = dc8 + q;
                float r = 1.f / (1.f + __expf(-lG[mi][d]));
                float z = 1.f / (1.f + __expf(-lG[mi][256 + d]));
                float narg = lN[mi][d] + r * lG[mi][512 + d];
                float nn = 1.f - 2.f / (__expf(2.f * narg) + 1.f);   // tanh
                float hp = (1.f - z) * nn + z * hreg[q];
                hreg[q] = hp;
                pk.c[q] = (signed char)__float2int_rn(fminf(fmaxf(hp, -1.f), 1.f) * 127.f);
            }
            *(int2*)(lA8 + mi * 272 + dc8) = pk.v2;
        }
        __syncthreads();
    }

    // epilogue: y = sigmoid((hF + se) . w_out + b_out), 32-lane reduce per batch
    {
        const float* sep = se + (size_t)(b0 + mi) * 256 + dc8;
        const float* wop = w_out + dc8;
        float p = 0.f;
        #pragma unroll
        for (int q = 0; q < 8; ++q) p += (hreg[q] + sep[q]) * wop[q];
        #pragma unroll
        for (int o = 16; o; o >>= 1) p += __shfl_xor(p, o);
        if ((tid & 31) == 0) out[b0 + mi] = 1.f / (1.f + __expf(-(p + b_out[0])));
    }
}

extern "C" void kernel_launch(void* const* d_in, const int* in_sizes, int n_in,
                              void* d_out, int out_size, void* d_ws, size_t ws_size,
                              hipStream_t stream) {
    const float* x1   = (const float*)d_in[0];
    const float* x2   = (const float*)d_in[1];
    const float* s    = (const float*)d_in[2];
    const float* w_e1 = (const float*)d_in[3];
    const float* b_e1 = (const float*)d_in[4];
    const float* w_e2 = (const float*)d_in[5];
    const float* b_e2 = (const float*)d_in[6];
    const float* w_s  = (const float*)d_in[7];
    const float* b_s  = (const float*)d_in[8];
    const float* w_x  = (const float*)d_in[9];
    const float* w_h  = (const float*)d_in[10];
    const float* b_h  = (const float*)d_in[11];
    const float* w_ih = (const float*)d_in[12];
    const float* w_hh = (const float*)d_in[13];
    const float* b_ih = (const float*)d_in[14];
    const float* b_hh = (const float*)d_in[15];
    const float* w_out = (const float*)d_in[16];
    const float* b_out = (const float*)d_in[17];
    float* out = (float*)d_out;

    char* ws = (char*)d_ws;
    size_t off = 0;
    auto alloc = [&](size_t bytes) -> void* {
        void* p = ws + off;
        off = (off + bytes + 255) & ~(size_t)255;
        return p;
    };
    short* xb = (short*)alloc((size_t)B_ * L_ * D_ * 2);
    signed char* W1q = (signed char*)alloc(896 * 256);   // 816 rows used; padded for prefetch
    signed char* W2q = (signed char*)alloc(768 * 256);
    float* qA = (float*)alloc(816 * 4);
    float* qC = (float*)alloc(768 * 4);
    float* c0 = (float*)alloc((size_t)B_ * L_ * 4);
    float* xw = (float*)alloc((size_t)B_ * L_ * 4);
    unsigned long long* cb = (unsigned long long*)alloc(B_ * 8);
    float* se = (float*)alloc((size_t)B_ * D_ * 4);

    hipLaunchKernelGGL(k_prep, dim3(396), dim3(256), 0, stream,
                       w_hh, w_h, w_ih, W1q, W2q, qA, qC);
    hipLaunchKernelGGL(k_embed, dim3(384), dim3(512), 0, stream,
                       x1, x2, w_e1, b_e1, w_e2, b_e2, xb);
    hipLaunchKernelGGL(k_aux, dim3(6144), dim3(256), 0, stream,
                       x2, w_e2, b_e2, xb, w_x, c0, xw);
    hipLaunchKernelGGL(k_aux2, dim3(512), dim3(256), 0, stream,
                       c0, s, w_s, b_s, cb, se);
    hipLaunchKernelGGL(k_scan, dim3(32), dim3(512), 0, stream,
                       W1q, W2q, qA, qC, b_hh, b_h, b_ih, xb, xw, cb, se, w_out, b_out, out);
}